// Round 11
// baseline (685.857 us; speedup 1.0000x reference)
//
#include <hip/hip_runtime.h>
#include <math.h>

typedef unsigned short u16;
typedef unsigned char u8;
typedef __bf16 bf16x8 __attribute__((ext_vector_type(8)));
typedef float f32x4 __attribute__((ext_vector_type(4)));
typedef unsigned short u16x4 __attribute__((ext_vector_type(4)));
typedef unsigned short u16x8 __attribute__((ext_vector_type(8)));

#define DEV static __device__ __forceinline__

DEV float bf2f(u16 u) { union { unsigned int i; float f; } x; x.i = ((unsigned int)u) << 16; return x.f; }
DEV u16 f2bf(float f) { union { float f; unsigned int i; } x; x.f = f; unsigned int r = x.i + 0x7fffu + ((x.i >> 16) & 1u); return (u16)(r >> 16); }

DEV void load_lds16(const void* g, void* l) {
  __builtin_amdgcn_global_load_lds((__attribute__((address_space(1))) void*)g,
                                   (__attribute__((address_space(3))) void*)l, 16, 0, 0);
}

// sigmoid-form tanh-GELU; |err vs erf-gelu| <= ~3e-3
DEV float gelu_tanh(float g) {
  float t = 0.7978845608f * g * (1.f + 0.044715f * g * g);
  return g / (1.f + __expf(-2.f * t));
}

// MFMA quadrant: MH/NH literals -> all acc indices compile-time (rule #20)
#define MMAQ(AREG, BREG, MH, NH)                                                            \
  do {                                                                                      \
    __builtin_amdgcn_s_setprio(1);                                                          \
    _Pragma("unroll") for (int m_ = 0; m_ < 4; ++m_)                                        \
      _Pragma("unroll") for (int n_ = 0; n_ < 2; ++n_)                                      \
        _Pragma("unroll") for (int kk_ = 0; kk_ < 2; ++kk_)                                 \
          acc[(MH)*4 + m_][(NH)*2 + n_] = __builtin_amdgcn_mfma_f32_16x16x32_bf16(          \
              AREG[m_][kk_], BREG[n_][kk_], acc[(MH)*4 + m_][(NH)*2 + n_], 0, 0, 0);        \
    __builtin_amdgcn_s_setprio(0);                                                          \
  } while (0)

// ---------------------------------------------------------------------------
// gemm256 v3: NT GEMM, 256x256 tile, BK=64, 512 thr = 8 waves (2M x 4N),
// 128KB LDS (2 x 64KB K-tile buffers). 8-phase (2 K-tiles) per iteration.
// Stall-free staging schedule (depth >= 4 phases, derived per-load):
//   quad(buf) = P1{LDA0,LDB0|bar|Q00|bar} P2{LDB1|bar|Q01|bar}
//               P3{LDA1, STG B0|bar|Q10|bar} P4{STG B1,A0,A1, Q11, vmcnt(8)|bar}
//   vmcnt(8) leaves only THIS quad's 8 stage-loads outstanding -> previous
//   quad's 8 (the buffer read next) are landed; never waits on fresh loads.
//   Region safety: each staged region's last ds_read completes >=1 barrier
//   before its stage (B free after P2, A free after P3).
// Tail iteration: no stages, vmcnt(0) at first quad's P4.
// M,N mult of 256; K mult of 128. EPI: 0 bf16 | 4 bias+gelu(tanh) bf16
// ---------------------------------------------------------------------------
template<int EPI>
__global__ __launch_bounds__(512, 1)
void gemm256(const u16* __restrict__ A, const u16* __restrict__ B, void* __restrict__ Cv,
             const float* __restrict__ aux0, const void* __restrict__ aux1,
             int M, int N, int K, int lda, int ldb, int ldc)
{
  __shared__ __align__(16) unsigned char smem[131072];
  const int tid = threadIdx.x;
  int bx = blockIdx.x, by = blockIdx.y;
  {
    const int GX = gridDim.x;
    const int nwg = GX * gridDim.y;
    if ((nwg & 7) == 0) {
      const int wg = by * GX + bx;
      const int cpx = nwg >> 3;
      const int xcd = wg & 7, s = wg >> 3;
      const int rows = cpx / GX;
      if ((GX & 7) == 0 && cpx == rows * GX && (rows & 7) == 0) {
        const int SC = GX >> 3;
        const int q = s >> 6, r = (s >> 3) & 7, c = s & 7;
        by = xcd * rows + (q / SC) * 8 + r;
        bx = (q % SC) * 8 + c;
      } else {
        const int swz = xcd * cpx + s;
        bx = swz % GX; by = swz / GX;
      }
    }
  }
  const int m0 = by * 256, n0 = bx * 256;
  const int wid = tid >> 6, lane = tid & 63;
  const int wr = wid >> 2, wc = wid & 3;
  const int ln15 = lane & 15, lq = lane >> 4;
  const int bhalf = wc >> 1;
  const int sRow = tid >> 3, sCh = tid & 7;

  f32x4 acc[8][4] = {};
  bf16x8 aR[4][2], b0R[2][2], b1R[2][2];

  // ---- staging sources (swizzled) + LDS dst bases ----
  const unsigned sc = (unsigned)((sCh ^ (sRow & 7)) << 4);
  const u8* gA0a = (const u8*)(A + (size_t)(m0 +       sRow) * lda) + sc;
  const u8* gA0b = (const u8*)(A + (size_t)(m0 +  64 + sRow) * lda) + sc;
  const u8* gA1a = (const u8*)(A + (size_t)(m0 + 128 + sRow) * lda) + sc;
  const u8* gA1b = (const u8*)(A + (size_t)(m0 + 192 + sRow) * lda) + sc;
  const u8* gB0a = (const u8*)(B + (size_t)(n0 +       sRow) * ldb) + sc;
  const u8* gB0b = (const u8*)(B + (size_t)(n0 +  64 + sRow) * ldb) + sc;
  const u8* gB1a = (const u8*)(B + (size_t)(n0 + 128 + sRow) * ldb) + sc;
  const u8* gB1b = (const u8*)(B + (size_t)(n0 + 192 + sRow) * ldb) + sc;
  const unsigned tb = (unsigned)(sRow * 128 + sCh * 16);
  const unsigned dA0 = tb, dA1 = tb + 16384, dB0 = tb + 65536, dB1 = tb + 81920;

  auto STG2 = [&](const u8* pa, const u8* pb, unsigned dst, unsigned bo, int kt) {
    load_lds16(pa + (size_t)kt * 128, smem + dst + bo);
    load_lds16(pb + (size_t)kt * 128, smem + dst + bo + 8192);
  };

  // ---- ds_read bases ----
  const unsigned swk0 = (unsigned)((lq ^ (ln15 & 7)) << 4);
  const unsigned swk1 = (unsigned)(((4 + lq) ^ (ln15 & 7)) << 4);
  const unsigned aOff0 = (unsigned)(wr * 16384 + ln15 * 128) + swk0;
  const unsigned aOff1 = (unsigned)(wr * 16384 + ln15 * 128) + swk1;
  const unsigned bOff0 = (unsigned)(65536 + bhalf * 16384 + ((wc & 1) * 64 + ln15) * 128) + swk0;
  const unsigned bOff1 = (unsigned)(65536 + bhalf * 16384 + ((wc & 1) * 64 + ln15) * 128) + swk1;
#define LDA(BO, MH)                                                                     \
  do { _Pragma("unroll") for (int m_ = 0; m_ < 4; ++m_) {                               \
    aR[m_][0] = *(const bf16x8*)(smem + aOff0 + (BO) + ((MH) * 8192 + m_ * 2048));      \
    aR[m_][1] = *(const bf16x8*)(smem + aOff1 + (BO) + ((MH) * 8192 + m_ * 2048));      \
  } } while (0)
#define LDB(BO, NH, BQ)                                                                 \
  do { _Pragma("unroll") for (int n_ = 0; n_ < 2; ++n_) {                               \
    BQ[n_][0] = *(const bf16x8*)(smem + bOff0 + (BO) + ((NH) * 4096 + n_ * 2048));      \
    BQ[n_][1] = *(const bf16x8*)(smem + bOff1 + (BO) + ((NH) * 4096 + n_ * 2048));      \
  } } while (0)

  // one K-tile = 4 phases. mode: 0 = stage ktN + vmcnt(8); 1 = no stage, vmcnt(0);
  // 2 = no stage, no vmcnt (final quad).
  auto quad = [&](unsigned BO, int ktN, int mode) {
    // P1
    LDA(BO, 0); LDB(BO, 0, b0R);
    __builtin_amdgcn_s_barrier();
    MMAQ(aR, b0R, 0, 0);
    __builtin_amdgcn_s_barrier();
    // P2
    LDB(BO, 1, b1R);
    __builtin_amdgcn_s_barrier();
    MMAQ(aR, b1R, 0, 1);
    __builtin_amdgcn_s_barrier();
    // P3
    LDA(BO, 1);
    if (mode == 0) STG2(gB0a, gB0b, dB0, BO, ktN);
    __builtin_amdgcn_s_barrier();
    MMAQ(aR, b0R, 1, 0);
    __builtin_amdgcn_s_barrier();
    // P4
    if (mode == 0) {
      STG2(gB1a, gB1b, dB1, BO, ktN);
      STG2(gA0a, gA0b, dA0, BO, ktN);
      STG2(gA1a, gA1b, dA1, BO, ktN);
    }
    MMAQ(aR, b1R, 1, 1);
    if (mode == 0)      asm volatile("s_waitcnt vmcnt(8)" ::: "memory");
    else if (mode == 1) asm volatile("s_waitcnt vmcnt(0)" ::: "memory");
    __builtin_amdgcn_s_barrier();
  };

  const int nkt = K >> 6, nit = nkt >> 1;

  // prologue: K-tile 0 -> buf0, K-tile 1 -> buf1
  STG2(gA0a, gA0b, dA0, 0, 0); STG2(gA1a, gA1b, dA1, 0, 0);
  STG2(gB0a, gB0b, dB0, 0, 0); STG2(gB1a, gB1b, dB1, 0, 0);
  STG2(gA0a, gA0b, dA0, 32768, 1); STG2(gA1a, gA1b, dA1, 32768, 1);
  STG2(gB0a, gB0b, dB0, 32768, 1); STG2(gB1a, gB1b, dB1, 32768, 1);
  asm volatile("s_waitcnt vmcnt(8)" ::: "memory");
  __builtin_amdgcn_s_barrier();

  for (int it = 0; it < nit; ++it) {
    const bool st = (it + 1 < nit);
    quad(0u,     2 * it + 2, st ? 0 : 1);
    quad(32768u, 2 * it + 3, st ? 0 : 2);
  }

  // ---- epilogue ----
#pragma unroll
  for (int m = 0; m < 8; ++m) {
#pragma unroll
    for (int n = 0; n < 4; ++n) {
      int col = n0 + wc * 64 + n * 16 + ln15;
#pragma unroll
      for (int j = 0; j < 4; ++j) {
        int row = m0 + wr * 128 + m * 16 + lq * 4 + j;
        float v = acc[m][n][j];
        size_t idx = (size_t)row * ldc + col;
        if (EPI == 0) {
          ((u16*)Cv)[idx] = f2bf(v);
        } else if (EPI == 4) {
          ((u16*)Cv)[idx] = f2bf(gelu_tanh(v + aux0[col]));
        }
      }
    }
  }
#undef LDA
#undef LDB
}

// ---------------------------------------------------------------------------
// Generic NT GEMM (proven): 128x128 tile, BK=64, 4 waves, XOR swizzle,
// XCD chunk + 8x8 sub-block raster (r10: FETCH 402->131MB on w1).
// EPI: 0 bf16 | 3 f32 v+aux0[col]+f32aux1[idx] | 4 bias+gelu(tanh) bf16 |
//      7 f32 v+aux0[col]+bf16aux1[idx]
// ---------------------------------------------------------------------------
template<int EPI>
__global__ __launch_bounds__(256, 2)
void gemm_nt(const u16* __restrict__ A, const u16* __restrict__ B, void* __restrict__ Cv,
             const float* __restrict__ aux0, const void* __restrict__ aux1,
             int M, int N, int K, int lda, int ldb, int ldc)
{
  __shared__ __align__(16) unsigned char smem[32768];
  const int tid = threadIdx.x;
  int bx = blockIdx.x, by = blockIdx.y;
  {
    const int GX = gridDim.x;
    const int nwg = GX * gridDim.y;
    if ((nwg & 7) == 0) {
      const int wg = by * GX + bx;
      const int cpx = nwg >> 3;
      const int xcd = wg & 7, s = wg >> 3;
      const int rows = cpx / GX;
      if ((GX & 7) == 0 && cpx == rows * GX && (rows & 7) == 0) {
        const int SC = GX >> 3;
        const int q = s >> 6, r = (s >> 3) & 7, c = s & 7;
        by = xcd * rows + (q / SC) * 8 + r;
        bx = (q % SC) * 8 + c;
      } else {
        const int swz = xcd * cpx + s;
        bx = swz % GX; by = swz / GX;
      }
    }
  }
  const int m0 = by * 128, n0 = bx * 128;
  const int wid = tid >> 6, lane = tid & 63;
  const int wr = wid >> 1, wc = wid & 1;
  const int ln15 = lane & 15, lq = lane >> 4;
  const int srow = tid >> 3, sch = tid & 7;

  f32x4 acc[4][4] = {};

  for (int k0 = 0; k0 < K; k0 += 64) {
#pragma unroll
    for (int i = 0; i < 4; ++i) {
      int r = i * 32 + srow;
      const unsigned char* src = (const unsigned char*)(A + (size_t)(m0 + r) * lda + k0) + ((sch ^ (r & 7)) << 4);
      load_lds16(src, smem + r * 128 + (sch << 4));
    }
#pragma unroll
    for (int i = 0; i < 4; ++i) {
      int r = i * 32 + srow;
      const unsigned char* src = (const unsigned char*)(B + (size_t)(n0 + r) * ldb + k0) + ((sch ^ (r & 7)) << 4);
      load_lds16(src, smem + 16384 + r * 128 + (sch << 4));
    }
    __syncthreads();
#pragma unroll
    for (int kk = 0; kk < 2; ++kk) {
      bf16x8 af[4], bfv[4];
#pragma unroll
      for (int m = 0; m < 4; ++m) {
        int r = wr * 64 + m * 16 + ln15;
        int kc = kk * 4 + lq;
        af[m] = *(const bf16x8*)(smem + r * 128 + ((kc ^ (r & 7)) << 4));
      }
#pragma unroll
      for (int n = 0; n < 4; ++n) {
        int r = wc * 64 + n * 16 + ln15;
        int kc = kk * 4 + lq;
        bfv[n] = *(const bf16x8*)(smem + 16384 + r * 128 + ((kc ^ (r & 7)) << 4));
      }
#pragma unroll
      for (int m = 0; m < 4; ++m)
#pragma unroll
        for (int n = 0; n < 4; ++n)
          acc[m][n] = __builtin_amdgcn_mfma_f32_16x16x32_bf16(af[m], bfv[n], acc[m][n], 0, 0, 0);
    }
    __syncthreads();
  }

#pragma unroll
  for (int m = 0; m < 4; ++m) {
#pragma unroll
    for (int n = 0; n < 4; ++n) {
      int col = n0 + wc * 64 + n * 16 + ln15;
#pragma unroll
      for (int j = 0; j < 4; ++j) {
        int row = m0 + wr * 64 + m * 16 + lq * 4 + j;
        float v = acc[m][n][j];
        size_t idx = (size_t)row * ldc + col;
        if (EPI == 0) {
          ((u16*)Cv)[idx] = f2bf(v);
        } else if (EPI == 3) {
          ((float*)Cv)[idx] = v + aux0[col] + ((const float*)aux1)[idx];
        } else if (EPI == 4) {
          ((u16*)Cv)[idx] = f2bf(gelu_tanh(v + aux0[col]));
        } else if (EPI == 7) {
          ((float*)Cv)[idx] = v + aux0[col] + bf2f(((const u16*)aux1)[idx]);
        }
      }
    }
  }
}

// ---------------------------------------------------------------------------
// fused_kv (proven r6): grid (8 chunks x 64 bh), software-pipelined dbuf.
// ---------------------------------------------------------------------------
__global__ __launch_bounds__(256, 2)
void fused_kv(const u16* __restrict__ qkv, const u16* __restrict__ projT,
              float* __restrict__ kvpart, float* __restrict__ ksumpart)
{
  __shared__ __align__(16) unsigned char ktS[2][8192];
  __shared__ __align__(16) unsigned char vtS[2][8192];
  __shared__ __align__(16) unsigned char kfS[32768];
  const int tid = threadIdx.x;
  const int bh = blockIdx.y, chunk = blockIdx.x;
  const int b = bh >> 4, h = bh & 15;
  const int wid = tid >> 6, lane = tid & 63;
  const int ln15 = lane & 15, lq = lane >> 4;
  const int vN = tid >> 2, vD = (tid & 3) * 16;
  const int vCn = vN >> 3, vWb = (vN & 7) * 2;

  bf16x8 pf[4][2];
#pragma unroll
  for (int m = 0; m < 4; ++m)
#pragma unroll
    for (int kk = 0; kk < 2; ++kk) {
      int f = wid * 64 + m * 16 + ln15;
      pf[m][kk] = *(const bf16x8*)(projT + (size_t)h * 16384 + (size_t)f * 64 + (kk * 4 + lq) * 8);
    }

  float ksum_r = 0.f;
  f32x4 acc2[4][4] = {};
  const int nbase = chunk * 512;

  {
    const u16* kg = qkv + ((size_t)b * 4096 + nbase) * 3072 + 1024 + h * 64;
#pragma unroll
    for (int i = 0; i < 2; ++i) {
      int c = i * 256 + tid; int r = c >> 3, ch = c & 7;
      load_lds16((const unsigned char*)(kg + (size_t)r * 3072) + ((ch ^ (r & 7)) << 4),
                 ktS[0] + r * 128 + ch * 16);
    }
    const u16* vg = qkv + ((size_t)b * 4096 + nbase + vN) * 3072 + 2048 + h * 64 + vD;
    u16x8 va = *(const u16x8*)vg;
    u16x8 vb = *(const u16x8*)(vg + 8);
#pragma unroll
    for (int j = 0; j < 8; ++j) {
      int d = vD + j;
      *(u16*)(vtS[0] + d * 128 + ((vCn ^ (d & 7)) << 4) + vWb) = va[j];
    }
#pragma unroll
    for (int j = 0; j < 8; ++j) {
      int d = vD + 8 + j;
      *(u16*)(vtS[0] + d * 128 + ((vCn ^ (d & 7)) << 4) + vWb) = vb[j];
    }
  }
  __syncthreads();

  for (int t = 0; t < 8; ++t) {
    const int cur = t & 1, nxt = cur ^ 1;
    u16x8 va, vb;
    const bool havenext = (t + 1 < 8);
    if (havenext) {
      int n1 = nbase + (t + 1) * 64;
      const u16* kg = qkv + ((size_t)b * 4096 + n1) * 3072 + 1024 + h * 64;
#pragma unroll
      for (int i = 0; i < 2; ++i) {
        int c = i * 256 + tid; int r = c >> 3, ch = c & 7;
        load_lds16((const unsigned char*)(kg + (size_t)r * 3072) + ((ch ^ (r & 7)) << 4),
                   ktS[nxt] + r * 128 + ch * 16);
      }
      const u16* vg = qkv + ((size_t)b * 4096 + n1 + vN) * 3072 + 2048 + h * 64 + vD;
      va = *(const u16x8*)vg;
      vb = *(const u16x8*)(vg + 8);
    }

    bf16x8 bvk[2][4];
#pragma unroll
    for (int kk = 0; kk < 2; ++kk)
#pragma unroll
      for (int n = 0; n < 4; ++n) {
        int r = n * 16 + ln15, kc = kk * 4 + lq;
        bvk[kk][n] = *(const bf16x8*)(ktS[cur] + r * 128 + ((kc ^ (r & 7)) << 4));
      }
#pragma unroll
    for (int m = 0; m < 4; ++m) {
      f32x4 a1[4] = {};
#pragma unroll
      for (int kk = 0; kk < 2; ++kk)
#pragma unroll
        for (int n = 0; n < 4; ++n)
          a1[n] = __builtin_amdgcn_mfma_f32_16x16x32_bf16(pf[m][kk], bvk[kk][n], a1[n], 0, 0, 0);
#pragma unroll
      for (int n = 0; n < 4; ++n) {
        int nloc = n * 16 + ln15;
        int c = nloc >> 3, wb = (nloc & 7) * 2;
#pragma unroll
        for (int j = 0; j < 4; ++j) {
          int f = wid * 64 + m * 16 + lq * 4 + j;
          float v = a1[n][j];
          float o = v > 0.f ? v + 1.f : __expf(v);
          *(u16*)(kfS + f * 128 + ((c ^ (f & 7)) << 4) + wb) = f2bf(o);
        }
      }
    }
    __syncthreads();

    {
      int f = tid;
      float s = 0.f;
#pragma unroll
      for (int c = 0; c < 8; ++c) {
        u16x8 v = *(const u16x8*)(kfS + f * 128 + ((c ^ (f & 7)) << 4));
#pragma unroll
        for (int j = 0; j < 8; ++j) s += bf2f(v[j]);
      }
      ksum_r += s;
    }
#pragma unroll
    for (int kk = 0; kk < 2; ++kk) {
      int kc = kk * 4 + lq;
      bf16x8 af[4], bv[4];
#pragma unroll
      for (int m = 0; m < 4; ++m) { int r = wid * 64 + m * 16 + ln15; af[m] = *(const bf16x8*)(kfS + r * 128 + ((kc ^ (r & 7)) << 4)); }
#pragma unroll
      for (int n = 0; n < 4; ++n) { int r = n * 16 + ln15; bv[n] = *(const bf16x8*)(vtS[cur] + r * 128 + ((kc ^ (r & 7)) << 4)); }
#pragma unroll
      for (int m = 0; m < 4; ++m)
#pragma unroll
        for (int n = 0; n < 4; ++n)
          acc2[m][n] = __builtin_amdgcn_mfma_f32_16x16x32_bf16(af[m], bv[n], acc2[m][n], 0, 0, 0);
    }
    if (havenext) {
#pragma unroll
      for (int j = 0; j < 8; ++j) {
        int d = vD + j;
        *(u16*)(vtS[nxt] + d * 128 + ((vCn ^ (d & 7)) << 4) + vWb) = va[j];
      }
#pragma unroll
      for (int j = 0; j < 8; ++j) {
        int d = vD + 8 + j;
        *(u16*)(vtS[nxt] + d * 128 + ((vCn ^ (d & 7)) << 4) + vWb) = vb[j];
      }
    }
    __syncthreads();
  }

  const size_t pbase = ((size_t)bh * 8 + chunk) * 16384;
#pragma unroll
  for (int half = 0; half < 2; ++half) {
#pragma unroll
    for (int m = 0; m < 4; ++m)
#pragma unroll
      for (int n2 = 0; n2 < 2; ++n2) {
        int n = half * 2 + n2;
        int dloc = n2 * 16 + ln15;
        int f = wid * 64 + m * 16 + lq * 4;
        *(f32x4*)(kfS + dloc * 1024 + ((f * 4) ^ ((dloc & 7) << 4))) = acc2[m][n];
      }
    __syncthreads();
#pragma unroll
    for (int k = 0; k < 8; ++k) {
      int dloc = k * 4 + wid;
      f32x4 val = *(const f32x4*)(kfS + dloc * 1024 + ((lane * 16) ^ ((dloc & 7) << 4)));
      *(f32x4*)(kvpart + pbase + (size_t)(half * 32 + dloc) * 256 + lane * 4) = val;
    }
    __syncthreads();
  }
  ksumpart[((size_t)bh * 8 + chunk) * 256 + tid] = ksum_r;
}

__global__ __launch_bounds__(256) void kv_finalize(const float* __restrict__ kvpart,
    const float* __restrict__ ksumpart, u16* __restrict__ kvT, float* __restrict__ ksum)
{
  int bx = blockIdx.x, bh = bx >> 2, dq = bx & 3, tid = threadIdx.x;
  const float* base = kvpart + (size_t)bh * 131072;
  u16* out = kvT + (size_t)bh * 16384;
#pragma unroll
  for (int k = 0; k < 16; ++k) {
    int idx = dq * 4096 + k * 256 + tid;
    float s = 0.f;
#pragma unroll
    for (int c = 0; c < 8; ++c) s += base[(size_t)c * 16384 + idx];
    out[idx] = f2bf(s);
  }
  if (dq == 0) {
    float s = 0.f;
#pragma unroll
    for (int c = 0; c < 8; ++c) s += ksumpart[((size_t)bh * 8 + c) * 256 + tid];
    ksum[(size_t)bh * 256 + tid] = s;
  }
}

__global__ __launch_bounds__(256, 3)
void fused_attn(const u16* __restrict__ qkv, const u16* __restrict__ projT,
                const u16* __restrict__ kvT, const float* __restrict__ ksum,
                u16* __restrict__ attnb)
{
  __shared__ __align__(16) unsigned char qtS[8192];
  __shared__ __align__(16) unsigned char qfS[32768];
  __shared__ float zpart[64][4];
  __shared__ float zS[64];
  const int tid = threadIdx.x;
  const int bh = blockIdx.y, nt = blockIdx.x;
  const int b = bh >> 4, h = bh & 15;
  const int wid = tid >> 6, lane = tid & 63;
  const int ln15 = lane & 15, lq = lane >> 4;
  const int n0 = nt * 64;

  bf16x8 pf[4][2];
#pragma unroll
  for (int n = 0; n < 4; ++n)
#pragma unroll
    for (int kk = 0; kk < 2; ++kk) {
      int f = wid * 64 + n * 16 + ln15;
      pf[n][kk] = *(const bf16x8*)(projT + (size_t)h * 16384 + (size_t)f * 64 + (kk * 4 + lq) * 8);
    }

  const u16* qg = qkv + ((size_t)b * 4096 + n0) * 3072 + h * 64;
#pragma unroll
  for (int i = 0; i < 2; ++i) {
    int c = i * 256 + tid; int r = c >> 3, ch = c & 7;
    load_lds16((const unsigned char*)(qg + (size_t)r * 3072) + ((ch ^ (r & 7)) << 4),
               qtS + r * 128 + ch * 16);
  }
  __syncthreads();

#pragma unroll
  for (int m = 0; m < 4; ++m) {
    bf16x8 af[2];
#pragma unroll
    for (int kk = 0; kk < 2; ++kk) {
      int r = m * 16 + ln15, kc = kk * 4 + lq;
      af[kk] = *(const bf16x8*)(qtS + r * 128 + ((kc ^ (r & 7)) << 4));
    }
    f32x4 a1[4] = {};
#pragma unroll
    for (int kk = 0; kk < 2; ++kk)
#pragma unroll
      for (int n = 0; n < 4; ++n)
        a1[n] = __builtin_amdgcn_mfma_f32_16x16x32_bf16(af[kk], pf[n][kk], a1[n], 0, 0, 0);
#pragma unroll
    for (int n = 0; n < 4; ++n) {
      int f = wid * 64 + n * 16 + ln15;
      int c = f >> 3, wb = (f & 7) * 2;
#pragma unroll
      for (int j = 0; j < 4; ++j) {
        int row = m * 16 + lq * 4 + j;
        float v = a1[n][j];
        float o = v > 0.f ? v + 1.f : __expf(v);
        *(u16*)(qfS + row * 512 + ((c ^ (row & 7)) << 4) + wb) = f2bf(o);
      }
    }
  }
  __syncthreads();

  {
    int n = tid & 63, q = tid >> 6;
    const float* kp = ksum + (size_t)bh * 256;
    float s = 0.f;
#pragma unroll
    for (int c = q * 8; c < q * 8 + 8; ++c) {
      u16x8 v = *(const u16x8*)(qfS + n * 512 + ((c ^ (n & 7)) << 4));
#pragma unroll
      for (int j = 0; j < 8; ++j) s += bf2f(v[j]) * kp[c * 8 + j];
    }
    zpart[n][q] = s;
  }
  __syncthreads();
  if (tid < 64) zS[tid] = 1.f / (zpart[tid][0] + zpart[tid][1] + zpart[tid][2] + zpart[tid][3] + 1e-8f);
  __syncthreads();

  f32x4 a2[4] = {};
  const u16* kvg = kvT + (size_t)bh * 16384;
#pragma unroll
  for (int kk = 0; kk < 8; ++kk) {
    int kc = kk * 4 + lq;
    int r = wid * 16 + ln15;
    bf16x8 af = *(const bf16x8*)(qfS + r * 512 + ((kc ^ (r & 7)) << 4));
#pragma unroll
    for (int nf = 0; nf < 4; ++nf) {
      int d = nf * 16 + ln15;
      bf16x8 bv = *(const bf16x8*)(kvg + (size_t)d * 256 + kc * 8);
      a2[nf] = __builtin_amdgcn_mfma_f32_16x16x32_bf16(af, bv, a2[nf], 0, 0, 0);
    }
  }
#pragma unroll
  for (int nf = 0; nf < 4; ++nf)
#pragma unroll
    for (int j = 0; j < 4; ++j) {
      int d = nf * 16 + ln15;
      int n = wid * 16 + lq * 4 + j;
      float v = a2[nf][j] * zS[n];
      attnb[((size_t)b * 4096 + n0 + n) * 1024 + h * 64 + d] = f2bf(v);
    }
}

__global__ __launch_bounds__(256) void cast_kernel(const float* __restrict__ in, u16* __restrict__ out, int n4)
{
  int i = blockIdx.x * 256 + threadIdx.x;
  if (i >= n4) return;
  float4 v = ((const float4*)in)[i];
  u16x4 o = { f2bf(v.x), f2bf(v.y), f2bf(v.z), f2bf(v.w) };
  ((u16x4*)out)[i] = o;
}

__global__ __launch_bounds__(256) void castw_kernel(const float* __restrict__ wqkv, const float* __restrict__ wout,
                                                    const float* __restrict__ w1, const float* __restrict__ w2,
                                                    u16* __restrict__ owqkv, u16* __restrict__ owout,
                                                    u16* __restrict__ ow1, u16* __restrict__ ow2)
{
  int bid = blockIdx.x;
  const float* src; u16* dst; int base;
  if (bid < 3072)      { src = wqkv; dst = owqkv; base = bid; }
  else if (bid < 4096) { src = wout; dst = owout; base = bid - 3072; }
  else if (bid < 8192) { src = w1;   dst = ow1;   base = bid - 4096; }
  else                 { src = w2;   dst = ow2;   base = bid - 8192; }
  int i = base * 256 + threadIdx.x;
  float4 v = ((const float4*)src)[i];
  u16x4 o = { f2bf(v.x), f2bf(v.y), f2bf(v.z), f2bf(v.w) };
  ((u16x4*)dst)[i] = o;
}

__global__ __launch_bounds__(256) void projt_kernel(const float* __restrict__ proj, u16* __restrict__ out)
{
  int i = blockIdx.x * 256 + threadIdx.x;
  int d = i & 63, f = (i >> 6) & 255, h = i >> 14;
  out[i] = f2bf(proj[((size_t)h * 64 + d) * 256 + f]);
}

__global__ __launch_bounds__(256) void ln_kernel(const float* __restrict__ in, const float* __restrict__ gamma,
                                                 const float* __restrict__ beta, float* __restrict__ outF,
                                                 u16* __restrict__ outB)
{
  int row = blockIdx.x, tid = threadIdx.x;
  float4 v = ((const float4*)(in + (size_t)row * 1024))[tid];
  float s = v.x + v.y + v.z + v.w;
  float q = v.x * v.x + v.y * v.y + v.z * v.z + v.w * v.w;
  for (int off = 32; off; off >>= 1) { s += __shfl_down(s, off); q += __shfl_down(q, off); }
  __shared__ float rs[4], rq[4];
  int wid = tid >> 6, lane = tid & 63;
  if (!lane) { rs[wid] = s; rq[wid] = q; }
  __syncthreads();
  s = rs[0] + rs[1] + rs[2] + rs[3];
  q = rq[0] + rq[1] + rq[2] + rq[3];
  float mu = s * (1.f / 1024.f);
  float rstd = rsqrtf(q * (1.f / 1024.f) - mu * mu + 1e-5f);
  float4 g = ((const float4*)gamma)[tid];
  float4 bb = ((const float4*)beta)[tid];
  float4 o;
  o.x = (v.x - mu) * rstd * g.x + bb.x;
  o.y = (v.y - mu) * rstd * g.y + bb.y;
  o.z = (v.z - mu) * rstd * g.z + bb.z;
  o.w = (v.w - mu) * rstd * g.w + bb.w;
  if (outF) ((float4*)(outF + (size_t)row * 1024))[tid] = o;
  if (outB) {
    u16x4 ob = { f2bf(o.x), f2bf(o.y), f2bf(o.z), f2bf(o.w) };
    ((u16x4*)(outB + (size_t)row * 1024))[tid] = ob;
  }
}

#define O_WQKVB   0L
#define O_WOUTB   6291456L
#define O_W1B     8388608L
#define O_W2B     16777216L
#define O_PROJT   25165824L
#define O_KSUM    25690112L
#define O_KSP     26804224L
#define O_KVB     27852800L
#define O_QFG     37289984L
#define O_QKVB    70844416L
#define O_ATTNB   171507712L
#define WS_NEED   205062144L

extern "C" void kernel_launch(void* const* d_in, const int* in_sizes, int n_in,
                              void* d_out, int out_size, void* d_ws, size_t ws_size,
                              hipStream_t stream)
{
  if (ws_size < (size_t)WS_NEED) return;

  const float* x     = (const float*)d_in[0];
  const float* proj  = (const float*)d_in[1];
  const float* wqkv  = (const float*)d_in[2];
  const float* wout  = (const float*)d_in[3];
  const float* bout  = (const float*)d_in[4];
  const float* gamma = (const float*)d_in[5];
  const float* beta  = (const float*)d_in[6];
  const float* w1    = (const float*)d_in[7];
  const float* b1    = (const float*)d_in[8];
  const float* w2    = (const float*)d_in[9];
  const float* b2    = (const float*)d_in[10];
  float* outp = (float*)d_out;
  char* ws = (char*)d_ws;

  u16* wqkvb  = (u16*)(ws + O_WQKVB);
  u16* woutb  = (u16*)(ws + O_WOUTB);
  u16* w1b    = (u16*)(ws + O_W1B);
  u16* w2b    = (u16*)(ws + O_W2B);
  u16* projTb = (u16*)(ws + O_PROJT);
  float* ksumf= (float*)(ws + O_KSUM);
  float* ksp  = (float*)(ws + O_KSP);
  u16* kvTb   = (u16*)(ws + O_KVB);
  float* kvp  = (float*)(ws + O_QFG);
  u16* x1b    = (u16*)(ws + O_QFG);
  u16* qkvb   = (u16*)(ws + O_QKVB);
  float* tf   = (float*)(ws + O_QKVB);
  u16* hfull  = (u16*)(ws + O_QKVB);
  u16* attnb  = (u16*)(ws + O_ATTNB);

  u16* xbD = (u16*)d_out;

  cast_kernel<<<16384, 256, 0, stream>>>(x, xbD, 4194304);
  castw_kernel<<<12288, 256, 0, stream>>>(wqkv, wout, w1, w2, wqkvb, woutb, w1b, w2b);
  projt_kernel<<<1024, 256, 0, stream>>>(proj, projTb);

  // qkv = x @ w_qkv^T : M=16384, N=3072, K=1024  (gemm256 v3)
  gemm256<0><<<dim3(12, 64), 512, 0, stream>>>(xbD, wqkvb, qkvb, nullptr, nullptr,
      16384, 3072, 1024, 1024, 1024, 3072);

  fused_kv<<<dim3(8, 64), 256, 0, stream>>>(qkvb, projTb, kvp, ksp);
  kv_finalize<<<256, 256, 0, stream>>>(kvp, ksp, kvTb, ksumf);
  fused_attn<<<dim3(64, 64), 256, 0, stream>>>(qkvb, projTb, kvTb, ksumf, attnb);

  // t = xb(bf16) + attn @ w_out^T + b_out : f32 -> tf
  gemm_nt<7><<<dim3(8, 128), 256, 0, stream>>>(attnb, woutb, tf, bout, xbD,
      16384, 1024, 1024, 1024, 1024, 1024);

  // x1 = LN(t): bf16 only
  ln_kernel<<<16384, 256, 0, stream>>>(tf, gamma, beta, nullptr, x1b);

  // h = gelu_tanh(x1 @ w1^T + b1) : M=16384, N=4096, K=1024  (gemm256 v3)
  gemm256<4><<<dim3(16, 64), 512, 0, stream>>>(x1b, w1b, hfull, b1, nullptr,
      16384, 4096, 1024, 1024, 1024, 4096);

  // y = x1(bf16) + h @ w2^T + b2 : f32 -> d_out
  gemm_nt<7><<<dim3(8, 128), 256, 0, stream>>>(hfull, w2b, outp, b2, x1b,
      16384, 1024, 4096, 4096, 4096, 1024);

  ln_kernel<<<16384, 256, 0, stream>>>(outp, gamma, beta, outp, nullptr);
}

// Round 12
// 653.540 us; speedup vs baseline: 1.0495x; 1.0495x over previous
//
#include <hip/hip_runtime.h>
#include <math.h>

typedef unsigned short u16;
typedef __bf16 bf16x8 __attribute__((ext_vector_type(8)));
typedef float f32x4 __attribute__((ext_vector_type(4)));
typedef unsigned short u16x4 __attribute__((ext_vector_type(4)));
typedef unsigned short u16x8 __attribute__((ext_vector_type(8)));

#define DEV static __device__ __forceinline__

DEV float bf2f(u16 u) { union { unsigned int i; float f; } x; x.i = ((unsigned int)u) << 16; return x.f; }
DEV u16 f2bf(float f) { union { float f; unsigned int i; } x; x.f = f; unsigned int r = x.i + 0x7fffu + ((x.i >> 16) & 1u); return (u16)(r >> 16); }

DEV void load_lds16(const void* g, void* l) {
  __builtin_amdgcn_global_load_lds((__attribute__((address_space(1))) void*)g,
                                   (__attribute__((address_space(3))) void*)l, 16, 0, 0);
}

// sigmoid-form tanh-GELU; |err vs erf-gelu| <= ~3e-3
DEV float gelu_tanh(float g) {
  float t = 0.7978845608f * g * (1.f + 0.044715f * g * g);
  return g / (1.f + __expf(-2.f * t));
}

// ---------------------------------------------------------------------------
// Generic NT GEMM (proven; ~900 TF structural ceiling of the 2-phase 128²
// m97-class structure): 128x128 tile, BK=64, 4 waves, MFMA 16x16x32,
// XOR swizzle both-sides (0 bank conflicts measured), XCD chunk + 8x8
// sub-block raster (r10: w1 FETCH 402->131MB, -12 us).
// EPI: 0 bf16 | 3 f32 v+aux0[col]+f32aux1[idx] | 4 bias+gelu(tanh) bf16 |
//      7 f32 v+aux0[col]+bf16aux1[idx]
// ---------------------------------------------------------------------------
template<int EPI>
__global__ __launch_bounds__(256, 2)
void gemm_nt(const u16* __restrict__ A, const u16* __restrict__ B, void* __restrict__ Cv,
             const float* __restrict__ aux0, const void* __restrict__ aux1,
             int M, int N, int K, int lda, int ldb, int ldc)
{
  __shared__ __align__(16) unsigned char smem[32768];
  const int tid = threadIdx.x;
  int bx = blockIdx.x, by = blockIdx.y;
  {
    const int GX = gridDim.x;
    const int nwg = GX * gridDim.y;
    if ((nwg & 7) == 0) {
      const int wg = by * GX + bx;
      const int cpx = nwg >> 3;
      const int xcd = wg & 7, s = wg >> 3;
      const int rows = cpx / GX;
      if ((GX & 7) == 0 && cpx == rows * GX && (rows & 7) == 0) {
        const int SC = GX >> 3;
        const int q = s >> 6, r = (s >> 3) & 7, c = s & 7;
        by = xcd * rows + (q / SC) * 8 + r;
        bx = (q % SC) * 8 + c;
      } else {
        const int swz = xcd * cpx + s;
        bx = swz % GX; by = swz / GX;
      }
    }
  }
  const int m0 = by * 128, n0 = bx * 128;
  const int wid = tid >> 6, lane = tid & 63;
  const int wr = wid >> 1, wc = wid & 1;
  const int ln15 = lane & 15, lq = lane >> 4;
  const int srow = tid >> 3, sch = tid & 7;

  f32x4 acc[4][4] = {};

  for (int k0 = 0; k0 < K; k0 += 64) {
#pragma unroll
    for (int i = 0; i < 4; ++i) {
      int r = i * 32 + srow;
      const unsigned char* src = (const unsigned char*)(A + (size_t)(m0 + r) * lda + k0) + ((sch ^ (r & 7)) << 4);
      load_lds16(src, smem + r * 128 + (sch << 4));
    }
#pragma unroll
    for (int i = 0; i < 4; ++i) {
      int r = i * 32 + srow;
      const unsigned char* src = (const unsigned char*)(B + (size_t)(n0 + r) * ldb + k0) + ((sch ^ (r & 7)) << 4);
      load_lds16(src, smem + 16384 + r * 128 + (sch << 4));
    }
    __syncthreads();
#pragma unroll
    for (int kk = 0; kk < 2; ++kk) {
      bf16x8 af[4], bfv[4];
#pragma unroll
      for (int m = 0; m < 4; ++m) {
        int r = wr * 64 + m * 16 + ln15;
        int kc = kk * 4 + lq;
        af[m] = *(const bf16x8*)(smem + r * 128 + ((kc ^ (r & 7)) << 4));
      }
#pragma unroll
      for (int n = 0; n < 4; ++n) {
        int r = wc * 64 + n * 16 + ln15;
        int kc = kk * 4 + lq;
        bfv[n] = *(const bf16x8*)(smem + 16384 + r * 128 + ((kc ^ (r & 7)) << 4));
      }
#pragma unroll
      for (int m = 0; m < 4; ++m)
#pragma unroll
        for (int n = 0; n < 4; ++n)
          acc[m][n] = __builtin_amdgcn_mfma_f32_16x16x32_bf16(af[m], bfv[n], acc[m][n], 0, 0, 0);
    }
    __syncthreads();
  }

#pragma unroll
  for (int m = 0; m < 4; ++m) {
#pragma unroll
    for (int n = 0; n < 4; ++n) {
      int col = n0 + wc * 64 + n * 16 + ln15;
#pragma unroll
      for (int j = 0; j < 4; ++j) {
        int row = m0 + wr * 64 + m * 16 + lq * 4 + j;
        float v = acc[m][n][j];
        size_t idx = (size_t)row * ldc + col;
        if (EPI == 0) {
          ((u16*)Cv)[idx] = f2bf(v);
        } else if (EPI == 3) {
          ((float*)Cv)[idx] = v + aux0[col] + ((const float*)aux1)[idx];
        } else if (EPI == 4) {
          ((u16*)Cv)[idx] = f2bf(gelu_tanh(v + aux0[col]));
        } else if (EPI == 7) {
          ((float*)Cv)[idx] = v + aux0[col] + bf2f(((const u16*)aux1)[idx]);
        }
      }
    }
  }
}

// ---------------------------------------------------------------------------
// fused_kv (proven r6): grid (8 chunks x 64 bh), software-pipelined dbuf.
// ---------------------------------------------------------------------------
__global__ __launch_bounds__(256, 2)
void fused_kv(const u16* __restrict__ qkv, const u16* __restrict__ projT,
              float* __restrict__ kvpart, float* __restrict__ ksumpart)
{
  __shared__ __align__(16) unsigned char ktS[2][8192];
  __shared__ __align__(16) unsigned char vtS[2][8192];
  __shared__ __align__(16) unsigned char kfS[32768];
  const int tid = threadIdx.x;
  const int bh = blockIdx.y, chunk = blockIdx.x;
  const int b = bh >> 4, h = bh & 15;
  const int wid = tid >> 6, lane = tid & 63;
  const int ln15 = lane & 15, lq = lane >> 4;
  const int vN = tid >> 2, vD = (tid & 3) * 16;
  const int vCn = vN >> 3, vWb = (vN & 7) * 2;

  bf16x8 pf[4][2];
#pragma unroll
  for (int m = 0; m < 4; ++m)
#pragma unroll
    for (int kk = 0; kk < 2; ++kk) {
      int f = wid * 64 + m * 16 + ln15;
      pf[m][kk] = *(const bf16x8*)(projT + (size_t)h * 16384 + (size_t)f * 64 + (kk * 4 + lq) * 8);
    }

  float ksum_r = 0.f;
  f32x4 acc2[4][4] = {};
  const int nbase = chunk * 512;

  {
    const u16* kg = qkv + ((size_t)b * 4096 + nbase) * 3072 + 1024 + h * 64;
#pragma unroll
    for (int i = 0; i < 2; ++i) {
      int c = i * 256 + tid; int r = c >> 3, ch = c & 7;
      load_lds16((const unsigned char*)(kg + (size_t)r * 3072) + ((ch ^ (r & 7)) << 4),
                 ktS[0] + r * 128 + ch * 16);
    }
    const u16* vg = qkv + ((size_t)b * 4096 + nbase + vN) * 3072 + 2048 + h * 64 + vD;
    u16x8 va = *(const u16x8*)vg;
    u16x8 vb = *(const u16x8*)(vg + 8);
#pragma unroll
    for (int j = 0; j < 8; ++j) {
      int d = vD + j;
      *(u16*)(vtS[0] + d * 128 + ((vCn ^ (d & 7)) << 4) + vWb) = va[j];
    }
#pragma unroll
    for (int j = 0; j < 8; ++j) {
      int d = vD + 8 + j;
      *(u16*)(vtS[0] + d * 128 + ((vCn ^ (d & 7)) << 4) + vWb) = vb[j];
    }
  }
  __syncthreads();

  for (int t = 0; t < 8; ++t) {
    const int cur = t & 1, nxt = cur ^ 1;
    u16x8 va, vb;
    const bool havenext = (t + 1 < 8);
    if (havenext) {
      int n1 = nbase + (t + 1) * 64;
      const u16* kg = qkv + ((size_t)b * 4096 + n1) * 3072 + 1024 + h * 64;
#pragma unroll
      for (int i = 0; i < 2; ++i) {
        int c = i * 256 + tid; int r = c >> 3, ch = c & 7;
        load_lds16((const unsigned char*)(kg + (size_t)r * 3072) + ((ch ^ (r & 7)) << 4),
                   ktS[nxt] + r * 128 + ch * 16);
      }
      const u16* vg = qkv + ((size_t)b * 4096 + n1 + vN) * 3072 + 2048 + h * 64 + vD;
      va = *(const u16x8*)vg;
      vb = *(const u16x8*)(vg + 8);
    }

    bf16x8 bvk[2][4];
#pragma unroll
    for (int kk = 0; kk < 2; ++kk)
#pragma unroll
      for (int n = 0; n < 4; ++n) {
        int r = n * 16 + ln15, kc = kk * 4 + lq;
        bvk[kk][n] = *(const bf16x8*)(ktS[cur] + r * 128 + ((kc ^ (r & 7)) << 4));
      }
#pragma unroll
    for (int m = 0; m < 4; ++m) {
      f32x4 a1[4] = {};
#pragma unroll
      for (int kk = 0; kk < 2; ++kk)
#pragma unroll
        for (int n = 0; n < 4; ++n)
          a1[n] = __builtin_amdgcn_mfma_f32_16x16x32_bf16(pf[m][kk], bvk[kk][n], a1[n], 0, 0, 0);
#pragma unroll
      for (int n = 0; n < 4; ++n) {
        int nloc = n * 16 + ln15;
        int c = nloc >> 3, wb = (nloc & 7) * 2;
#pragma unroll
        for (int j = 0; j < 4; ++j) {
          int f = wid * 64 + m * 16 + lq * 4 + j;
          float v = a1[n][j];
          float o = v > 0.f ? v + 1.f : __expf(v);
          *(u16*)(kfS + f * 128 + ((c ^ (f & 7)) << 4) + wb) = f2bf(o);
        }
      }
    }
    __syncthreads();

    {
      int f = tid;
      float s = 0.f;
#pragma unroll
      for (int c = 0; c < 8; ++c) {
        u16x8 v = *(const u16x8*)(kfS + f * 128 + ((c ^ (f & 7)) << 4));
#pragma unroll
        for (int j = 0; j < 8; ++j) s += bf2f(v[j]);
      }
      ksum_r += s;
    }
#pragma unroll
    for (int kk = 0; kk < 2; ++kk) {
      int kc = kk * 4 + lq;
      bf16x8 af[4], bv[4];
#pragma unroll
      for (int m = 0; m < 4; ++m) { int r = wid * 64 + m * 16 + ln15; af[m] = *(const bf16x8*)(kfS + r * 128 + ((kc ^ (r & 7)) << 4)); }
#pragma unroll
      for (int n = 0; n < 4; ++n) { int r = n * 16 + ln15; bv[n] = *(const bf16x8*)(vtS[cur] + r * 128 + ((kc ^ (r & 7)) << 4)); }
#pragma unroll
      for (int m = 0; m < 4; ++m)
#pragma unroll
        for (int n = 0; n < 4; ++n)
          acc2[m][n] = __builtin_amdgcn_mfma_f32_16x16x32_bf16(af[m], bv[n], acc2[m][n], 0, 0, 0);
    }
    if (havenext) {
#pragma unroll
      for (int j = 0; j < 8; ++j) {
        int d = vD + j;
        *(u16*)(vtS[nxt] + d * 128 + ((vCn ^ (d & 7)) << 4) + vWb) = va[j];
      }
#pragma unroll
      for (int j = 0; j < 8; ++j) {
        int d = vD + 8 + j;
        *(u16*)(vtS[nxt] + d * 128 + ((vCn ^ (d & 7)) << 4) + vWb) = vb[j];
      }
    }
    __syncthreads();
  }

  const size_t pbase = ((size_t)bh * 8 + chunk) * 16384;
#pragma unroll
  for (int half = 0; half < 2; ++half) {
#pragma unroll
    for (int m = 0; m < 4; ++m)
#pragma unroll
      for (int n2 = 0; n2 < 2; ++n2) {
        int n = half * 2 + n2;
        int dloc = n2 * 16 + ln15;
        int f = wid * 64 + m * 16 + lq * 4;
        *(f32x4*)(kfS + dloc * 1024 + ((f * 4) ^ ((dloc & 7) << 4))) = acc2[m][n];
      }
    __syncthreads();
#pragma unroll
    for (int k = 0; k < 8; ++k) {
      int dloc = k * 4 + wid;
      f32x4 val = *(const f32x4*)(kfS + dloc * 1024 + ((lane * 16) ^ ((dloc & 7) << 4)));
      *(f32x4*)(kvpart + pbase + (size_t)(half * 32 + dloc) * 256 + lane * 4) = val;
    }
    __syncthreads();
  }
  ksumpart[((size_t)bh * 8 + chunk) * 256 + tid] = ksum_r;
}

__global__ __launch_bounds__(256) void kv_finalize(const float* __restrict__ kvpart,
    const float* __restrict__ ksumpart, u16* __restrict__ kvT, float* __restrict__ ksum)
{
  int bx = blockIdx.x, bh = bx >> 2, dq = bx & 3, tid = threadIdx.x;
  const float* base = kvpart + (size_t)bh * 131072;
  u16* out = kvT + (size_t)bh * 16384;
#pragma unroll
  for (int k = 0; k < 16; ++k) {
    int idx = dq * 4096 + k * 256 + tid;
    float s = 0.f;
#pragma unroll
    for (int c = 0; c < 8; ++c) s += base[(size_t)c * 16384 + idx];
    out[idx] = f2bf(s);
  }
  if (dq == 0) {
    float s = 0.f;
#pragma unroll
    for (int c = 0; c < 8; ++c) s += ksumpart[((size_t)bh * 8 + c) * 256 + tid];
    ksum[(size_t)bh * 256 + tid] = s;
  }
}

__global__ __launch_bounds__(256, 3)
void fused_attn(const u16* __restrict__ qkv, const u16* __restrict__ projT,
                const u16* __restrict__ kvT, const float* __restrict__ ksum,
                u16* __restrict__ attnb)
{
  __shared__ __align__(16) unsigned char qtS[8192];
  __shared__ __align__(16) unsigned char qfS[32768];
  __shared__ float zpart[64][4];
  __shared__ float zS[64];
  const int tid = threadIdx.x;
  const int bh = blockIdx.y, nt = blockIdx.x;
  const int b = bh >> 4, h = bh & 15;
  const int wid = tid >> 6, lane = tid & 63;
  const int ln15 = lane & 15, lq = lane >> 4;
  const int n0 = nt * 64;

  bf16x8 pf[4][2];
#pragma unroll
  for (int n = 0; n < 4; ++n)
#pragma unroll
    for (int kk = 0; kk < 2; ++kk) {
      int f = wid * 64 + n * 16 + ln15;
      pf[n][kk] = *(const bf16x8*)(projT + (size_t)h * 16384 + (size_t)f * 64 + (kk * 4 + lq) * 8);
    }

  const u16* qg = qkv + ((size_t)b * 4096 + n0) * 3072 + h * 64;
#pragma unroll
  for (int i = 0; i < 2; ++i) {
    int c = i * 256 + tid; int r = c >> 3, ch = c & 7;
    load_lds16((const unsigned char*)(qg + (size_t)r * 3072) + ((ch ^ (r & 7)) << 4),
               qtS + r * 128 + ch * 16);
  }
  __syncthreads();

#pragma unroll
  for (int m = 0; m < 4; ++m) {
    bf16x8 af[2];
#pragma unroll
    for (int kk = 0; kk < 2; ++kk) {
      int r = m * 16 + ln15, kc = kk * 4 + lq;
      af[kk] = *(const bf16x8*)(qtS + r * 128 + ((kc ^ (r & 7)) << 4));
    }
    f32x4 a1[4] = {};
#pragma unroll
    for (int kk = 0; kk < 2; ++kk)
#pragma unroll
      for (int n = 0; n < 4; ++n)
        a1[n] = __builtin_amdgcn_mfma_f32_16x16x32_bf16(af[kk], pf[n][kk], a1[n], 0, 0, 0);
#pragma unroll
    for (int n = 0; n < 4; ++n) {
      int f = wid * 64 + n * 16 + ln15;
      int c = f >> 3, wb = (f & 7) * 2;
#pragma unroll
      for (int j = 0; j < 4; ++j) {
        int row = m * 16 + lq * 4 + j;
        float v = a1[n][j];
        float o = v > 0.f ? v + 1.f : __expf(v);
        *(u16*)(qfS + row * 512 + ((c ^ (row & 7)) << 4) + wb) = f2bf(o);
      }
    }
  }
  __syncthreads();

  {
    int n = tid & 63, q = tid >> 6;
    const float* kp = ksum + (size_t)bh * 256;
    float s = 0.f;
#pragma unroll
    for (int c = q * 8; c < q * 8 + 8; ++c) {
      u16x8 v = *(const u16x8*)(qfS + n * 512 + ((c ^ (n & 7)) << 4));
#pragma unroll
      for (int j = 0; j < 8; ++j) s += bf2f(v[j]) * kp[c * 8 + j];
    }
    zpart[n][q] = s;
  }
  __syncthreads();
  if (tid < 64) zS[tid] = 1.f / (zpart[tid][0] + zpart[tid][1] + zpart[tid][2] + zpart[tid][3] + 1e-8f);
  __syncthreads();

  f32x4 a2[4] = {};
  const u16* kvg = kvT + (size_t)bh * 16384;
#pragma unroll
  for (int kk = 0; kk < 8; ++kk) {
    int kc = kk * 4 + lq;
    int r = wid * 16 + ln15;
    bf16x8 af = *(const bf16x8*)(qfS + r * 512 + ((kc ^ (r & 7)) << 4));
#pragma unroll
    for (int nf = 0; nf < 4; ++nf) {
      int d = nf * 16 + ln15;
      bf16x8 bv = *(const bf16x8*)(kvg + (size_t)d * 256 + kc * 8);
      a2[nf] = __builtin_amdgcn_mfma_f32_16x16x32_bf16(af, bv, a2[nf], 0, 0, 0);
    }
  }
#pragma unroll
  for (int nf = 0; nf < 4; ++nf)
#pragma unroll
    for (int j = 0; j < 4; ++j) {
      int d = nf * 16 + ln15;
      int n = wid * 16 + lq * 4 + j;
      float v = a2[nf][j] * zS[n];
      attnb[((size_t)b * 4096 + n0 + n) * 1024 + h * 64 + d] = f2bf(v);
    }
}

// all f32->bf16 input casts in ONE launch: 28672 blocks
// [0,16384) x | [16384,19456) wqkv | [19456,20480) wout | [20480,24576) w1 | [24576,28672) w2
__global__ __launch_bounds__(256) void cast_all(const float* __restrict__ x, const float* __restrict__ wqkv,
                                                const float* __restrict__ wout, const float* __restrict__ w1,
                                                const float* __restrict__ w2,
                                                u16* __restrict__ ox, u16* __restrict__ owqkv,
                                                u16* __restrict__ owout, u16* __restrict__ ow1,
                                                u16* __restrict__ ow2)
{
  int bid = blockIdx.x;
  const float* src; u16* dst; int base;
  if (bid < 16384)      { src = x;    dst = ox;    base = bid; }
  else if (bid < 19456) { src = wqkv; dst = owqkv; base = bid - 16384; }
  else if (bid < 20480) { src = wout; dst = owout; base = bid - 19456; }
  else if (bid < 24576) { src = w1;   dst = ow1;   base = bid - 20480; }
  else                  { src = w2;   dst = ow2;   base = bid - 24576; }
  int i = base * 256 + threadIdx.x;
  float4 v = ((const float4*)src)[i];
  u16x4 o = { f2bf(v.x), f2bf(v.y), f2bf(v.z), f2bf(v.w) };
  ((u16x4*)dst)[i] = o;
}

__global__ __launch_bounds__(256) void projt_kernel(const float* __restrict__ proj, u16* __restrict__ out)
{
  int i = blockIdx.x * 256 + threadIdx.x;
  int d = i & 63, f = (i >> 6) & 255, h = i >> 14;
  out[i] = f2bf(proj[((size_t)h * 64 + d) * 256 + f]);
}

// LayerNorm over 1024 f32; outF (f32) and outB (bf16) each optional.
__global__ __launch_bounds__(256) void ln_kernel(const float* __restrict__ in, const float* __restrict__ gamma,
                                                 const float* __restrict__ beta, float* __restrict__ outF,
                                                 u16* __restrict__ outB)
{
  int row = blockIdx.x, tid = threadIdx.x;
  float4 v = ((const float4*)(in + (size_t)row * 1024))[tid];
  float s = v.x + v.y + v.z + v.w;
  float q = v.x * v.x + v.y * v.y + v.z * v.z + v.w * v.w;
  for (int off = 32; off; off >>= 1) { s += __shfl_down(s, off); q += __shfl_down(q, off); }
  __shared__ float rs[4], rq[4];
  int wid = tid >> 6, lane = tid & 63;
  if (!lane) { rs[wid] = s; rq[wid] = q; }
  __syncthreads();
  s = rs[0] + rs[1] + rs[2] + rs[3];
  q = rq[0] + rq[1] + rq[2] + rq[3];
  float mu = s * (1.f / 1024.f);
  float rstd = rsqrtf(q * (1.f / 1024.f) - mu * mu + 1e-5f);
  float4 g = ((const float4*)gamma)[tid];
  float4 bb = ((const float4*)beta)[tid];
  float4 o;
  o.x = (v.x - mu) * rstd * g.x + bb.x;
  o.y = (v.y - mu) * rstd * g.y + bb.y;
  o.z = (v.z - mu) * rstd * g.z + bb.z;
  o.w = (v.w - mu) * rstd * g.w + bb.w;
  if (outF) ((float4*)(outF + (size_t)row * 1024))[tid] = o;
  if (outB) {
    u16x4 ob = { f2bf(o.x), f2bf(o.y), f2bf(o.z), f2bf(o.w) };
    ((u16x4*)(outB + (size_t)row * 1024))[tid] = ob;
  }
}

// ---------------------------------------------------------------------------
// Buffer plan (ws 205 MB + d_out 67 MB as scratch):
//   d_out: xb (bf16 x) — alive until outproj reads it as residual; then w2
//          overwrites d_out with the final f32.
//   ws O_QFG  (33.5MB): kvpart f32 (fused_kv) -> then x1b (bf16, LN1 out)
//   ws O_QKVB (134MB) : qkvb -> then tf (outproj f32, 67MB) -> then hfull
//   ws O_ATTNB (33.5MB): attnb
// ---------------------------------------------------------------------------
#define O_WQKVB   0L
#define O_WOUTB   6291456L
#define O_W1B     8388608L
#define O_W2B     16777216L
#define O_PROJT   25165824L
#define O_KSUM    25690112L
#define O_KSP     26804224L
#define O_KVB     27852800L
#define O_QFG     37289984L
#define O_QKVB    70844416L
#define O_ATTNB   171507712L
#define WS_NEED   205062144L

extern "C" void kernel_launch(void* const* d_in, const int* in_sizes, int n_in,
                              void* d_out, int out_size, void* d_ws, size_t ws_size,
                              hipStream_t stream)
{
  if (ws_size < (size_t)WS_NEED) return;

  const float* x     = (const float*)d_in[0];
  const float* proj  = (const float*)d_in[1];
  const float* wqkv  = (const float*)d_in[2];
  const float* wout  = (const float*)d_in[3];
  const float* bout  = (const float*)d_in[4];
  const float* gamma = (const float*)d_in[5];
  const float* beta  = (const float*)d_in[6];
  const float* w1    = (const float*)d_in[7];
  const float* b1    = (const float*)d_in[8];
  const float* w2    = (const float*)d_in[9];
  const float* b2    = (const float*)d_in[10];
  float* outp = (float*)d_out;
  char* ws = (char*)d_ws;

  u16* wqkvb  = (u16*)(ws + O_WQKVB);
  u16* woutb  = (u16*)(ws + O_WOUTB);
  u16* w1b    = (u16*)(ws + O_W1B);
  u16* w2b    = (u16*)(ws + O_W2B);
  u16* projTb = (u16*)(ws + O_PROJT);
  float* ksumf= (float*)(ws + O_KSUM);
  float* ksp  = (float*)(ws + O_KSP);
  u16* kvTb   = (u16*)(ws + O_KVB);
  float* kvp  = (float*)(ws + O_QFG);     // dead after kv_finalize
  u16* x1b    = (u16*)(ws + O_QFG);       // reuses kvp region
  u16* qkvb   = (u16*)(ws + O_QKVB);      // dead after fused_attn
  float* tf   = (float*)(ws + O_QKVB);    // outproj f32 out, dead after LN1
  u16* hfull  = (u16*)(ws + O_QKVB);      // 134MB, overlays tf after LN1
  u16* attnb  = (u16*)(ws + O_ATTNB);

  u16* xbD = (u16*)d_out;                 // bf16 x, alive until outproj

  cast_all<<<28672, 256, 0, stream>>>(x, wqkv, wout, w1, w2, xbD, wqkvb, woutb, w1b, w2b);
  projt_kernel<<<1024, 256, 0, stream>>>(proj, projTb);

  // qkv = x @ w_qkv^T : M=16384, N=3072, K=1024
  gemm_nt<0><<<dim3(24, 128), 256, 0, stream>>>(xbD, wqkvb, qkvb, nullptr, nullptr,
      16384, 3072, 1024, 1024, 1024, 3072);

  fused_kv<<<dim3(8, 64), 256, 0, stream>>>(qkvb, projTb, kvp, ksp);
  kv_finalize<<<256, 256, 0, stream>>>(kvp, ksp, kvTb, ksumf);
  fused_attn<<<dim3(64, 64), 256, 0, stream>>>(qkvb, projTb, kvTb, ksumf, attnb);

  // t = xb(bf16) + attn @ w_out^T + b_out : f32 -> tf (ws; qkvb dead)
  gemm_nt<7><<<dim3(8, 128), 256, 0, stream>>>(attnb, woutb, tf, bout, xbD,
      16384, 1024, 1024, 1024, 1024, 1024);

  // x1 = LN(t): bf16 only
  ln_kernel<<<16384, 256, 0, stream>>>(tf, gamma, beta, nullptr, x1b);

  // h = gelu_tanh(x1 @ w1^T + b1) : M=16384, N=4096, K=1024
  gemm_nt<4><<<dim3(32, 128), 256, 0, stream>>>(x1b, w1b, hfull, b1, nullptr,
      16384, 4096, 1024, 1024, 1024, 4096);

  // y = x1(bf16) + h @ w2^T + b2 : f32 -> d_out (xb dead, full overwrite)
  gemm_nt<7><<<dim3(8, 128), 256, 0, stream>>>(hfull, w2b, outp, b2, x1b,
      16384, 1024, 4096, 4096, 4096, 1024);

  ln_kernel<<<16384, 256, 0, stream>>>(outp, gamma, beta, outp, nullptr);
}

// Round 14
// 649.619 us; speedup vs baseline: 1.0558x; 1.0060x over previous
//
#include <hip/hip_runtime.h>
#include <math.h>

typedef unsigned short u16;
typedef __bf16 bf16x8 __attribute__((ext_vector_type(8)));
typedef float f32x4 __attribute__((ext_vector_type(4)));
typedef unsigned short u16x4 __attribute__((ext_vector_type(4)));
typedef unsigned short u16x8 __attribute__((ext_vector_type(8)));

#define DEV static __device__ __forceinline__

DEV float bf2f(u16 u) { union { unsigned int i; float f; } x; x.i = ((unsigned int)u) << 16; return x.f; }
DEV u16 f2bf(float f) { union { float f; unsigned int i; } x; x.f = f; unsigned int r = x.i + 0x7fffu + ((x.i >> 16) & 1u); return (u16)(r >> 16); }

DEV void load_lds16(const void* g, void* l) {
  __builtin_amdgcn_global_load_lds((__attribute__((address_space(1))) void*)g,
                                   (__attribute__((address_space(3))) void*)l, 16, 0, 0);
}

// sigmoid-form tanh-GELU; |err vs erf-gelu| <= ~3e-3
DEV float gelu_tanh(float g) {
  float t = 0.7978845608f * g * (1.f + 0.044715f * g * g);
  return g / (1.f + __expf(-2.f * t));
}

// ---------------------------------------------------------------------------
// Generic NT GEMM (proven; ~900 TF structural ceiling of the 2-phase 128²
// m97-class structure): 128x128 tile, BK=64, 4 waves, MFMA 16x16x32,
// XOR swizzle both-sides (0 bank conflicts measured), XCD chunk + 8x8
// sub-block raster (r10: w1 FETCH 402->131MB).
// EPI: 0 bf16 | 4 bias+gelu(tanh) bf16 | 7 f32 v+aux0[col]+bf16aux1[idx] |
//      8 bf16 v+aux0[col]+bf16aux1[idx]
// ---------------------------------------------------------------------------
template<int EPI>
__global__ __launch_bounds__(256, 2)
void gemm_nt(const u16* __restrict__ A, const u16* __restrict__ B, void* __restrict__ Cv,
             const float* __restrict__ aux0, const void* __restrict__ aux1,
             int M, int N, int K, int lda, int ldb, int ldc)
{
  __shared__ __align__(16) unsigned char smem[32768];
  const int tid = threadIdx.x;
  int bx = blockIdx.x, by = blockIdx.y;
  {
    const int GX = gridDim.x;
    const int nwg = GX * gridDim.y;
    if ((nwg & 7) == 0) {
      const int wg = by * GX + bx;
      const int cpx = nwg >> 3;
      const int xcd = wg & 7, s = wg >> 3;
      const int rows = cpx / GX;
      if ((GX & 7) == 0 && cpx == rows * GX && (rows & 7) == 0) {
        const int SC = GX >> 3;
        const int q = s >> 6, r = (s >> 3) & 7, c = s & 7;
        by = xcd * rows + (q / SC) * 8 + r;
        bx = (q % SC) * 8 + c;
      } else {
        const int swz = xcd * cpx + s;
        bx = swz % GX; by = swz / GX;
      }
    }
  }
  const int m0 = by * 128, n0 = bx * 128;
  const int wid = tid >> 6, lane = tid & 63;
  const int wr = wid >> 1, wc = wid & 1;
  const int ln15 = lane & 15, lq = lane >> 4;
  const int srow = tid >> 3, sch = tid & 7;

  f32x4 acc[4][4] = {};

  for (int k0 = 0; k0 < K; k0 += 64) {
#pragma unroll
    for (int i = 0; i < 4; ++i) {
      int r = i * 32 + srow;
      const unsigned char* src = (const unsigned char*)(A + (size_t)(m0 + r) * lda + k0) + ((sch ^ (r & 7)) << 4);
      load_lds16(src, smem + r * 128 + (sch << 4));
    }
#pragma unroll
    for (int i = 0; i < 4; ++i) {
      int r = i * 32 + srow;
      const unsigned char* src = (const unsigned char*)(B + (size_t)(n0 + r) * ldb + k0) + ((sch ^ (r & 7)) << 4);
      load_lds16(src, smem + 16384 + r * 128 + (sch << 4));
    }
    __syncthreads();
#pragma unroll
    for (int kk = 0; kk < 2; ++kk) {
      bf16x8 af[4], bfv[4];
#pragma unroll
      for (int m = 0; m < 4; ++m) {
        int r = wr * 64 + m * 16 + ln15;
        int kc = kk * 4 + lq;
        af[m] = *(const bf16x8*)(smem + r * 128 + ((kc ^ (r & 7)) << 4));
      }
#pragma unroll
      for (int n = 0; n < 4; ++n) {
        int r = wc * 64 + n * 16 + ln15;
        int kc = kk * 4 + lq;
        bfv[n] = *(const bf16x8*)(smem + 16384 + r * 128 + ((kc ^ (r & 7)) << 4));
      }
#pragma unroll
      for (int m = 0; m < 4; ++m)
#pragma unroll
        for (int n = 0; n < 4; ++n)
          acc[m][n] = __builtin_amdgcn_mfma_f32_16x16x32_bf16(af[m], bfv[n], acc[m][n], 0, 0, 0);
    }
    __syncthreads();
  }

#pragma unroll
  for (int m = 0; m < 4; ++m) {
#pragma unroll
    for (int n = 0; n < 4; ++n) {
      int col = n0 + wc * 64 + n * 16 + ln15;
#pragma unroll
      for (int j = 0; j < 4; ++j) {
        int row = m0 + wr * 64 + m * 16 + lq * 4 + j;
        float v = acc[m][n][j];
        size_t idx = (size_t)row * ldc + col;
        if (EPI == 0) {
          ((u16*)Cv)[idx] = f2bf(v);
        } else if (EPI == 4) {
          ((u16*)Cv)[idx] = f2bf(gelu_tanh(v + aux0[col]));
        } else if (EPI == 7) {
          ((float*)Cv)[idx] = v + aux0[col] + bf2f(((const u16*)aux1)[idx]);
        } else if (EPI == 8) {
          ((u16*)Cv)[idx] = f2bf(v + aux0[col] + bf2f(((const u16*)aux1)[idx]));
        }
      }
    }
  }
}

// ---------------------------------------------------------------------------
// fused_kv (proven r6): grid (8 chunks x 64 bh), software-pipelined dbuf.
// ---------------------------------------------------------------------------
__global__ __launch_bounds__(256, 2)
void fused_kv(const u16* __restrict__ qkv, const u16* __restrict__ projT,
              float* __restrict__ kvpart, float* __restrict__ ksumpart)
{
  __shared__ __align__(16) unsigned char ktS[2][8192];
  __shared__ __align__(16) unsigned char vtS[2][8192];
  __shared__ __align__(16) unsigned char kfS[32768];
  const int tid = threadIdx.x;
  const int bh = blockIdx.y, chunk = blockIdx.x;
  const int b = bh >> 4, h = bh & 15;
  const int wid = tid >> 6, lane = tid & 63;
  const int ln15 = lane & 15, lq = lane >> 4;
  const int vN = tid >> 2, vD = (tid & 3) * 16;
  const int vCn = vN >> 3, vWb = (vN & 7) * 2;

  bf16x8 pf[4][2];
#pragma unroll
  for (int m = 0; m < 4; ++m)
#pragma unroll
    for (int kk = 0; kk < 2; ++kk) {
      int f = wid * 64 + m * 16 + ln15;
      pf[m][kk] = *(const bf16x8*)(projT + (size_t)h * 16384 + (size_t)f * 64 + (kk * 4 + lq) * 8);
    }

  float ksum_r = 0.f;
  f32x4 acc2[4][4] = {};
  const int nbase = chunk * 512;

  {
    const u16* kg = qkv + ((size_t)b * 4096 + nbase) * 3072 + 1024 + h * 64;
#pragma unroll
    for (int i = 0; i < 2; ++i) {
      int c = i * 256 + tid; int r = c >> 3, ch = c & 7;
      load_lds16((const unsigned char*)(kg + (size_t)r * 3072) + ((ch ^ (r & 7)) << 4),
                 ktS[0] + r * 128 + ch * 16);
    }
    const u16* vg = qkv + ((size_t)b * 4096 + nbase + vN) * 3072 + 2048 + h * 64 + vD;
    u16x8 va = *(const u16x8*)vg;
    u16x8 vb = *(const u16x8*)(vg + 8);
#pragma unroll
    for (int j = 0; j < 8; ++j) {
      int d = vD + j;
      *(u16*)(vtS[0] + d * 128 + ((vCn ^ (d & 7)) << 4) + vWb) = va[j];
    }
#pragma unroll
    for (int j = 0; j < 8; ++j) {
      int d = vD + 8 + j;
      *(u16*)(vtS[0] + d * 128 + ((vCn ^ (d & 7)) << 4) + vWb) = vb[j];
    }
  }
  __syncthreads();

  for (int t = 0; t < 8; ++t) {
    const int cur = t & 1, nxt = cur ^ 1;
    u16x8 va, vb;
    const bool havenext = (t + 1 < 8);
    if (havenext) {
      int n1 = nbase + (t + 1) * 64;
      const u16* kg = qkv + ((size_t)b * 4096 + n1) * 3072 + 1024 + h * 64;
#pragma unroll
      for (int i = 0; i < 2; ++i) {
        int c = i * 256 + tid; int r = c >> 3, ch = c & 7;
        load_lds16((const unsigned char*)(kg + (size_t)r * 3072) + ((ch ^ (r & 7)) << 4),
                   ktS[nxt] + r * 128 + ch * 16);
      }
      const u16* vg = qkv + ((size_t)b * 4096 + n1 + vN) * 3072 + 2048 + h * 64 + vD;
      va = *(const u16x8*)vg;
      vb = *(const u16x8*)(vg + 8);
    }

    bf16x8 bvk[2][4];
#pragma unroll
    for (int kk = 0; kk < 2; ++kk)
#pragma unroll
      for (int n = 0; n < 4; ++n) {
        int r = n * 16 + ln15, kc = kk * 4 + lq;
        bvk[kk][n] = *(const bf16x8*)(ktS[cur] + r * 128 + ((kc ^ (r & 7)) << 4));
      }
#pragma unroll
    for (int m = 0; m < 4; ++m) {
      f32x4 a1[4] = {};
#pragma unroll
      for (int kk = 0; kk < 2; ++kk)
#pragma unroll
        for (int n = 0; n < 4; ++n)
          a1[n] = __builtin_amdgcn_mfma_f32_16x16x32_bf16(pf[m][kk], bvk[kk][n], a1[n], 0, 0, 0);
#pragma unroll
      for (int n = 0; n < 4; ++n) {
        int nloc = n * 16 + ln15;
        int c = nloc >> 3, wb = (nloc & 7) * 2;
#pragma unroll
        for (int j = 0; j < 4; ++j) {
          int f = wid * 64 + m * 16 + lq * 4 + j;
          float v = a1[n][j];
          float o = v > 0.f ? v + 1.f : __expf(v);
          *(u16*)(kfS + f * 128 + ((c ^ (f & 7)) << 4) + wb) = f2bf(o);
        }
      }
    }
    __syncthreads();

    {
      int f = tid;
      float s = 0.f;
#pragma unroll
      for (int c = 0; c < 8; ++c) {
        u16x8 v = *(const u16x8*)(kfS + f * 128 + ((c ^ (f & 7)) << 4));
#pragma unroll
        for (int j = 0; j < 8; ++j) s += bf2f(v[j]);
      }
      ksum_r += s;
    }
#pragma unroll
    for (int kk = 0; kk < 2; ++kk) {
      int kc = kk * 4 + lq;
      bf16x8 af[4], bv[4];
#pragma unroll
      for (int m = 0; m < 4; ++m) { int r = wid * 64 + m * 16 + ln15; af[m] = *(const bf16x8*)(kfS + r * 128 + ((kc ^ (r & 7)) << 4)); }
#pragma unroll
      for (int n = 0; n < 4; ++n) { int r = n * 16 + ln15; bv[n] = *(const bf16x8*)(vtS[cur] + r * 128 + ((kc ^ (r & 7)) << 4)); }
#pragma unroll
      for (int m = 0; m < 4; ++m)
#pragma unroll
        for (int n = 0; n < 4; ++n)
          acc2[m][n] = __builtin_amdgcn_mfma_f32_16x16x32_bf16(af[m], bv[n], acc2[m][n], 0, 0, 0);
    }
    if (havenext) {
#pragma unroll
      for (int j = 0; j < 8; ++j) {
        int d = vD + j;
        *(u16*)(vtS[nxt] + d * 128 + ((vCn ^ (d & 7)) << 4) + vWb) = va[j];
      }
#pragma unroll
      for (int j = 0; j < 8; ++j) {
        int d = vD + 8 + j;
        *(u16*)(vtS[nxt] + d * 128 + ((vCn ^ (d & 7)) << 4) + vWb) = vb[j];
      }
    }
    __syncthreads();
  }

  const size_t pbase = ((size_t)bh * 8 + chunk) * 16384;
#pragma unroll
  for (int half = 0; half < 2; ++half) {
#pragma unroll
    for (int m = 0; m < 4; ++m)
#pragma unroll
      for (int n2 = 0; n2 < 2; ++n2) {
        int n = half * 2 + n2;
        int dloc = n2 * 16 + ln15;
        int f = wid * 64 + m * 16 + lq * 4;
        *(f32x4*)(kfS + dloc * 1024 + ((f * 4) ^ ((dloc & 7) << 4))) = acc2[m][n];
      }
    __syncthreads();
#pragma unroll
    for (int k = 0; k < 8; ++k) {
      int dloc = k * 4 + wid;
      f32x4 val = *(const f32x4*)(kfS + dloc * 1024 + ((lane * 16) ^ ((dloc & 7) << 4)));
      *(f32x4*)(kvpart + pbase + (size_t)(half * 32 + dloc) * 256 + lane * 4) = val;
    }
    __syncthreads();
  }
  ksumpart[((size_t)bh * 8 + chunk) * 256 + tid] = ksum_r;
}

__global__ __launch_bounds__(256) void kv_finalize(const float* __restrict__ kvpart,
    const float* __restrict__ ksumpart, u16* __restrict__ kvT, float* __restrict__ ksum)
{
  int bx = blockIdx.x, bh = bx >> 2, dq = bx & 3, tid = threadIdx.x;
  const float* base = kvpart + (size_t)bh * 131072;
  u16* out = kvT + (size_t)bh * 16384;
#pragma unroll
  for (int k = 0; k < 16; ++k) {
    int idx = dq * 4096 + k * 256 + tid;
    float s = 0.f;
#pragma unroll
    for (int c = 0; c < 8; ++c) s += base[(size_t)c * 16384 + idx];
    out[idx] = f2bf(s);
  }
  if (dq == 0) {
    float s = 0.f;
#pragma unroll
    for (int c = 0; c < 8; ++c) s += ksumpart[((size_t)bh * 8 + c) * 256 + tid];
    ksum[(size_t)bh * 256 + tid] = s;
  }
}

__global__ __launch_bounds__(256, 3)
void fused_attn(const u16* __restrict__ qkv, const u16* __restrict__ projT,
                const u16* __restrict__ kvT, const float* __restrict__ ksum,
                u16* __restrict__ attnb)
{
  __shared__ __align__(16) unsigned char qtS[8192];
  __shared__ __align__(16) unsigned char qfS[32768];
  __shared__ float zpart[64][4];
  __shared__ float zS[64];
  const int tid = threadIdx.x;
  const int bh = blockIdx.y, nt = blockIdx.x;
  const int b = bh >> 4, h = bh & 15;
  const int wid = tid >> 6, lane = tid & 63;
  const int ln15 = lane & 15, lq = lane >> 4;
  const int n0 = nt * 64;

  bf16x8 pf[4][2];
#pragma unroll
  for (int n = 0; n < 4; ++n)
#pragma unroll
    for (int kk = 0; kk < 2; ++kk) {
      int f = wid * 64 + n * 16 + ln15;
      pf[n][kk] = *(const bf16x8*)(projT + (size_t)h * 16384 + (size_t)f * 64 + (kk * 4 + lq) * 8);
    }

  const u16* qg = qkv + ((size_t)b * 4096 + n0) * 3072 + h * 64;
#pragma unroll
  for (int i = 0; i < 2; ++i) {
    int c = i * 256 + tid; int r = c >> 3, ch = c & 7;
    load_lds16((const unsigned char*)(qg + (size_t)r * 3072) + ((ch ^ (r & 7)) << 4),
               qtS + r * 128 + ch * 16);
  }
  __syncthreads();

#pragma unroll
  for (int m = 0; m < 4; ++m) {
    bf16x8 af[2];
#pragma unroll
    for (int kk = 0; kk < 2; ++kk) {
      int r = m * 16 + ln15, kc = kk * 4 + lq;
      af[kk] = *(const bf16x8*)(qtS + r * 128 + ((kc ^ (r & 7)) << 4));
    }
    f32x4 a1[4] = {};
#pragma unroll
    for (int kk = 0; kk < 2; ++kk)
#pragma unroll
      for (int n = 0; n < 4; ++n)
        a1[n] = __builtin_amdgcn_mfma_f32_16x16x32_bf16(af[kk], pf[n][kk], a1[n], 0, 0, 0);
#pragma unroll
    for (int n = 0; n < 4; ++n) {
      int f = wid * 64 + n * 16 + ln15;
      int c = f >> 3, wb = (f & 7) * 2;
#pragma unroll
      for (int j = 0; j < 4; ++j) {
        int row = m * 16 + lq * 4 + j;
        float v = a1[n][j];
        float o = v > 0.f ? v + 1.f : __expf(v);
        *(u16*)(qfS + row * 512 + ((c ^ (row & 7)) << 4) + wb) = f2bf(o);
      }
    }
  }
  __syncthreads();

  {
    int n = tid & 63, q = tid >> 6;
    const float* kp = ksum + (size_t)bh * 256;
    float s = 0.f;
#pragma unroll
    for (int c = q * 8; c < q * 8 + 8; ++c) {
      u16x8 v = *(const u16x8*)(qfS + n * 512 + ((c ^ (n & 7)) << 4));
#pragma unroll
      for (int j = 0; j < 8; ++j) s += bf2f(v[j]) * kp[c * 8 + j];
    }
    zpart[n][q] = s;
  }
  __syncthreads();
  if (tid < 64) zS[tid] = 1.f / (zpart[tid][0] + zpart[tid][1] + zpart[tid][2] + zpart[tid][3] + 1e-8f);
  __syncthreads();

  f32x4 a2[4] = {};
  const u16* kvg = kvT + (size_t)bh * 16384;
#pragma unroll
  for (int kk = 0; kk < 8; ++kk) {
    int kc = kk * 4 + lq;
    int r = wid * 16 + ln15;
    bf16x8 af = *(const bf16x8*)(qfS + r * 512 + ((kc ^ (r & 7)) << 4));
#pragma unroll
    for (int nf = 0; nf < 4; ++nf) {
      int d = nf * 16 + ln15;
      bf16x8 bv = *(const bf16x8*)(kvg + (size_t)d * 256 + kc * 8);
      a2[nf] = __builtin_amdgcn_mfma_f32_16x16x32_bf16(af, bv, a2[nf], 0, 0, 0);
    }
  }
#pragma unroll
  for (int nf = 0; nf < 4; ++nf)
#pragma unroll
    for (int j = 0; j < 4; ++j) {
      int d = nf * 16 + ln15;
      int n = wid * 16 + lq * 4 + j;
      float v = a2[nf][j] * zS[n];
      attnb[((size_t)b * 4096 + n0 + n) * 1024 + h * 64 + d] = f2bf(v);
    }
}

// all f32->bf16 input casts in ONE launch: 28672 blocks
__global__ __launch_bounds__(256) void cast_all(const float* __restrict__ x, const float* __restrict__ wqkv,
                                                const float* __restrict__ wout, const float* __restrict__ w1,
                                                const float* __restrict__ w2,
                                                u16* __restrict__ ox, u16* __restrict__ owqkv,
                                                u16* __restrict__ owout, u16* __restrict__ ow1,
                                                u16* __restrict__ ow2)
{
  int bid = blockIdx.x;
  const float* src; u16* dst; int base;
  if (bid < 16384)      { src = x;    dst = ox;    base = bid; }
  else if (bid < 19456) { src = wqkv; dst = owqkv; base = bid - 16384; }
  else if (bid < 20480) { src = wout; dst = owout; base = bid - 19456; }
  else if (bid < 24576) { src = w1;   dst = ow1;   base = bid - 20480; }
  else                  { src = w2;   dst = ow2;   base = bid - 24576; }
  int i = base * 256 + threadIdx.x;
  float4 v = ((const float4*)src)[i];
  u16x4 o = { f2bf(v.x), f2bf(v.y), f2bf(v.z), f2bf(v.w) };
  ((u16x4*)dst)[i] = o;
}

__global__ __launch_bounds__(256) void projt_kernel(const float* __restrict__ proj, u16* __restrict__ out)
{
  int i = blockIdx.x * 256 + threadIdx.x;
  int d = i & 63, f = (i >> 6) & 255, h = i >> 14;
  out[i] = f2bf(proj[((size_t)h * 64 + d) * 256 + f]);
}

// LayerNorm over 1024 BF16 inputs -> bf16 out (LN1 path)
__global__ __launch_bounds__(256) void ln_bf16in(const u16* __restrict__ in, const float* __restrict__ gamma,
                                                 const float* __restrict__ beta, u16* __restrict__ outB)
{
  int row = blockIdx.x, tid = threadIdx.x;
  u16x4 vb = ((const u16x4*)(in + (size_t)row * 1024))[tid];
  float4 v = { bf2f(vb[0]), bf2f(vb[1]), bf2f(vb[2]), bf2f(vb[3]) };
  float s = v.x + v.y + v.z + v.w;
  float q = v.x * v.x + v.y * v.y + v.z * v.z + v.w * v.w;
  for (int off = 32; off; off >>= 1) { s += __shfl_down(s, off); q += __shfl_down(q, off); }
  __shared__ float rs[4], rq[4];
  int wid = tid >> 6, lane = tid & 63;
  if (!lane) { rs[wid] = s; rq[wid] = q; }
  __syncthreads();
  s = rs[0] + rs[1] + rs[2] + rs[3];
  q = rq[0] + rq[1] + rq[2] + rq[3];
  float mu = s * (1.f / 1024.f);
  float rstd = rsqrtf(q * (1.f / 1024.f) - mu * mu + 1e-5f);
  float4 g = ((const float4*)gamma)[tid];
  float4 bb = ((const float4*)beta)[tid];
  u16x4 ob = { f2bf((v.x - mu) * rstd * g.x + bb.x),
               f2bf((v.y - mu) * rstd * g.y + bb.y),
               f2bf((v.z - mu) * rstd * g.z + bb.z),
               f2bf((v.w - mu) * rstd * g.w + bb.w) };
  ((u16x4*)(outB + (size_t)row * 1024))[tid] = ob;
}

// LayerNorm over 1024 f32, in-place safe (same-row RMW only) — LN2 path
__global__ __launch_bounds__(256) void ln_f32(const float* __restrict__ in, const float* __restrict__ gamma,
                                              const float* __restrict__ beta, float* __restrict__ outF)
{
  int row = blockIdx.x, tid = threadIdx.x;
  float4 v = ((const float4*)(in + (size_t)row * 1024))[tid];
  float s = v.x + v.y + v.z + v.w;
  float q = v.x * v.x + v.y * v.y + v.z * v.z + v.w * v.w;
  for (int off = 32; off; off >>= 1) { s += __shfl_down(s, off); q += __shfl_down(q, off); }
  __shared__ float rs[4], rq[4];
  int wid = tid >> 6, lane = tid & 63;
  if (!lane) { rs[wid] = s; rq[wid] = q; }
  __syncthreads();
  s = rs[0] + rs[1] + rs[2] + rs[3];
  q = rq[0] + rq[1] + rq[2] + rq[3];
  float mu = s * (1.f / 1024.f);
  float rstd = rsqrtf(q * (1.f / 1024.f) - mu * mu + 1e-5f);
  float4 g = ((const float4*)gamma)[tid];
  float4 bb = ((const float4*)beta)[tid];
  float4 o;
  o.x = (v.x - mu) * rstd * g.x + bb.x;
  o.y = (v.y - mu) * rstd * g.y + bb.y;
  o.z = (v.z - mu) * rstd * g.z + bb.z;
  o.w = (v.w - mu) * rstd * g.w + bb.w;
  ((float4*)(outF + (size_t)row * 1024))[tid] = o;
}

// ---------------------------------------------------------------------------
// Buffer plan (ws 205 MB + d_out 67 MB as scratch):
//   d_out: xb (bf16 x) — alive until outproj; then w2 overwrites d_out f32;
//          LN2 runs f32 in-place (same-row RMW, safe).
//   ws O_QFG  (33.5MB): kvpart f32 -> then x1b (bf16, LN1 out)
//   ws O_QKVB (134MB) : qkvb -> tfb (outproj bf16, 33.5MB) -> hfull
//   ws O_ATTNB (33.5MB): attnb  (NOTE: inside hfull's span — must stay
//                        read-only once hfull is live; no writes here. r13's
//                        yb-write-into-hfull race is reverted.)
// ---------------------------------------------------------------------------
#define O_WQKVB   0L
#define O_WOUTB   6291456L
#define O_W1B     8388608L
#define O_W2B     16777216L
#define O_PROJT   25165824L
#define O_KSUM    25690112L
#define O_KSP     26804224L
#define O_KVB     27852800L
#define O_QFG     37289984L
#define O_QKVB    70844416L
#define O_ATTNB   171507712L
#define WS_NEED   205062144L

extern "C" void kernel_launch(void* const* d_in, const int* in_sizes, int n_in,
                              void* d_out, int out_size, void* d_ws, size_t ws_size,
                              hipStream_t stream)
{
  if (ws_size < (size_t)WS_NEED) return;

  const float* x     = (const float*)d_in[0];
  const float* proj  = (const float*)d_in[1];
  const float* wqkv  = (const float*)d_in[2];
  const float* wout  = (const float*)d_in[3];
  const float* bout  = (const float*)d_in[4];
  const float* gamma = (const float*)d_in[5];
  const float* beta  = (const float*)d_in[6];
  const float* w1    = (const float*)d_in[7];
  const float* b1    = (const float*)d_in[8];
  const float* w2    = (const float*)d_in[9];
  const float* b2    = (const float*)d_in[10];
  float* outp = (float*)d_out;
  char* ws = (char*)d_ws;

  u16* wqkvb  = (u16*)(ws + O_WQKVB);
  u16* woutb  = (u16*)(ws + O_WOUTB);
  u16* w1b    = (u16*)(ws + O_W1B);
  u16* w2b    = (u16*)(ws + O_W2B);
  u16* projTb = (u16*)(ws + O_PROJT);
  float* ksumf= (float*)(ws + O_KSUM);
  float* ksp  = (float*)(ws + O_KSP);
  u16* kvTb   = (u16*)(ws + O_KVB);
  float* kvp  = (float*)(ws + O_QFG);     // dead after kv_finalize
  u16* x1b    = (u16*)(ws + O_QFG);       // reuses kvp region
  u16* qkvb   = (u16*)(ws + O_QKVB);      // dead after fused_attn
  u16* tfb    = (u16*)(ws + O_QKVB);      // outproj bf16 out, dead after LN1
  u16* hfull  = (u16*)(ws + O_QKVB);      // 134MB, overlays tfb after LN1
  u16* attnb  = (u16*)(ws + O_ATTNB);     // dead after outproj

  u16* xbD = (u16*)d_out;                 // bf16 x, alive until outproj

  cast_all<<<28672, 256, 0, stream>>>(x, wqkv, wout, w1, w2, xbD, wqkvb, woutb, w1b, w2b);
  projt_kernel<<<1024, 256, 0, stream>>>(proj, projTb);

  // qkv = x @ w_qkv^T : M=16384, N=3072, K=1024
  gemm_nt<0><<<dim3(24, 128), 256, 0, stream>>>(xbD, wqkvb, qkvb, nullptr, nullptr,
      16384, 3072, 1024, 1024, 1024, 3072);

  fused_kv<<<dim3(8, 64), 256, 0, stream>>>(qkvb, projTb, kvp, ksp);
  kv_finalize<<<256, 256, 0, stream>>>(kvp, ksp, kvTb, ksumf);
  fused_attn<<<dim3(64, 64), 256, 0, stream>>>(qkvb, projTb, kvTb, ksumf, attnb);

  // t = xb(bf16) + attn @ w_out^T + b_out : bf16 -> tfb (ws; qkvb dead)
  gemm_nt<8><<<dim3(8, 128), 256, 0, stream>>>(attnb, woutb, tfb, bout, xbD,
      16384, 1024, 1024, 1024, 1024, 1024);

  // x1 = LN(t): bf16 in -> bf16 out
  ln_bf16in<<<16384, 256, 0, stream>>>(tfb, gamma, beta, x1b);

  // h = gelu_tanh(x1 @ w1^T + b1) : M=16384, N=4096, K=1024 (hfull overlays tfb)
  gemm_nt<4><<<dim3(32, 128), 256, 0, stream>>>(x1b, w1b, hfull, b1, nullptr,
      16384, 4096, 1024, 1024, 1024, 4096);

  // y = x1(bf16) + h @ w2^T + b2 : f32 -> d_out (xb dead, full overwrite)
  gemm_nt<7><<<dim3(8, 128), 256, 0, stream>>>(hfull, w2b, outp, b2, x1b,
      16384, 1024, 4096, 4096, 4096, 1024);

  // final LN: f32 in-place on d_out
  ln_f32<<<16384, 256, 0, stream>>>(outp, gamma, beta, outp);
}